// Round 1
// baseline (3384.050 us; speedup 1.0000x reference)
//
#include <hip/hip_runtime.h>
#include <hip/hip_bf16.h>
#include <stdint.h>
#include <math.h>

// ---------------- constants ----------------
constexpr int NN   = 16384;   // N = L*M
constexpr int NM   = 5120;    // n (measurements)
constexpr int B    = 500;     // batch
constexpr int BP   = 512;     // padded batch
constexpr int LSEC = 512;     // sections
constexpr int MSEC = 32;      // section size
constexpr float SIGMA2 = 0.2f;
constexpr float SCALE  = 3.1622776601683795f; // sqrt(n*P/L) = sqrt(10)
constexpr int ITERS = 4;

// ---------------- workspace layout (bytes) — needs ~426 MB ----------------
constexpr size_t OFF_A16 = 0;                                  // f16 A [5120][16384]
constexpr size_t SZ_A16  = (size_t)NM * NN * 2;
constexpr size_t OFF_W16 = OFF_A16 + SZ_A16;                   // f16 W [16384][5120]
constexpr size_t SZ_W16  = (size_t)NN * NM * 2;
constexpr size_t OFF_UT  = OFF_W16 + SZ_W16;                   // f16 u^T [512][16384]
constexpr size_t SZ_UT   = (size_t)BP * NN * 2;
constexpr size_t OFF_TT  = OFF_UT + SZ_UT;                     // f16 t^T [512][5120]
constexpr size_t SZ_TT   = (size_t)BP * NM * 2;
constexpr size_t OFF_R   = OFF_TT + SZ_TT;                     // f32 r [16384][512]
constexpr size_t SZ_R    = (size_t)NN * BP * 4;
constexpr size_t OFF_S   = OFF_R + SZ_R;                       // f32 s [16384][512]
constexpr size_t SZ_S    = (size_t)NN * BP * 4;
constexpr size_t OFF_SC  = OFF_S + SZ_S;                       // scalars + coef[512]

typedef _Float16 f16x8 __attribute__((ext_vector_type(8)));
typedef float    f32x4 __attribute__((ext_vector_type(4)));

struct H4 { _Float16 a, b, c, d; };

// global -> LDS direct copy, 16 B per lane. LDS dst must be wave-uniform;
// HW writes lane's 16B at (base + lane*16).
typedef const uint32_t __attribute__((address_space(1)))* gp_t;
typedef uint32_t       __attribute__((address_space(3)))* lp_t;
__device__ __forceinline__ void g2l16(const void* g, void* l) {
    __builtin_amdgcn_global_load_lds((gp_t)(uintptr_t)g,
                                     (lp_t)(uint32_t)(uintptr_t)l, 16, 0, 0);
}

// ---------------- kernels ----------------
__global__ void init_scalars(float* sc) {
    if (threadIdx.x < 2) sc[threadIdx.x] = 0.0f;
}

// fp32 -> fp16 convert, fused sum-of-squares reduction (taa / tww)
__global__ __launch_bounds__(256) void convert_f16_sq(
        const float* __restrict__ src, _Float16* __restrict__ dst,
        size_t n4, float* __restrict__ accum) {
    size_t i = (size_t)blockIdx.x * blockDim.x + threadIdx.x;
    size_t stride = (size_t)gridDim.x * blockDim.x;
    float sum = 0.0f;
    for (size_t j = i; j < n4; j += stride) {
        const float4 v = ((const float4*)src)[j];
        sum = fmaf(v.x, v.x, fmaf(v.y, v.y, fmaf(v.z, v.z, fmaf(v.w, v.w, sum))));
        H4 h { (_Float16)v.x, (_Float16)v.y, (_Float16)v.z, (_Float16)v.w };
        ((H4*)dst)[j] = h;
    }
    #pragma unroll
    for (int o = 32; o > 0; o >>= 1) sum += __shfl_down(sum, o);
    if ((threadIdx.x & 63) == 0) atomicAdd(accum, sum);
}

// u0^T[b][k] = f16(x[k][b] - s_in[k][b]), zero-padded for b >= 500
__global__ __launch_bounds__(128) void make_u0T(
        const float* __restrict__ x, const float* __restrict__ s,
        _Float16* __restrict__ uT) {
    int j  = blockIdx.x;                    // section
    int b  = blockIdx.y * 128 + threadIdx.x;
    int m0 = j * MSEC;
    _Float16 vals[MSEC];
    if (b < B) {
        #pragma unroll
        for (int i = 0; i < MSEC; ++i) {
            size_t idx = (size_t)(m0 + i) * B + b;
            vals[i] = (_Float16)(x[idx] - s[idx]);
        }
    } else {
        #pragma unroll
        for (int i = 0; i < MSEC; ++i) vals[i] = (_Float16)0.0f;
    }
    f16x8* dst = (f16x8*)&uT[(size_t)b * NN + m0];
    const f16x8* v8 = (const f16x8*)vals;
    #pragma unroll
    for (int c = 0; c < 4; ++c) dst[c] = v8[c];
}

// MODE 0: t-GEMM  C[5120,512] = A16 @ u  (+noise) -> write t^T fp16
// MODE 1: r-GEMM  C[16384,512] = W16 @ t ; r = s + g*C -> write r fp32
template <int MODE>
__global__ __launch_bounds__(256) void gemm_kern(
        const _Float16* __restrict__ Amat, const _Float16* __restrict__ BT, int K,
        const float* __restrict__ noise, _Float16* __restrict__ tT,
        const float* __restrict__ sprev, int s_ld,
        const float* __restrict__ gamma, int iter, float* __restrict__ r) {
    __shared__ _Float16 sA[128 * 64];   // [m][k]
    __shared__ _Float16 sB[128 * 64];   // [n][k]
    const int tid  = threadIdx.x;
    const int lane = tid & 63;
    const int wave = tid >> 6;
    const int wm = wave >> 1, wn = wave & 1;       // 2x2 wave grid, 64x64 each
    const size_t m0 = (size_t)blockIdx.x * 128;
    const int    n0 = blockIdx.y * 128;
    const int r16 = lane & 15, q = lane >> 4;

    f32x4 acc[4][4] = {};

    for (int k0 = 0; k0 < K; k0 += 64) {
        #pragma unroll
        for (int j = 0; j < 4; ++j) {
            int chunk = wave * 4 + j;             // 0..15, wave-uniform
            int eoff  = chunk * 512 + lane * 8;   // half index in 128x64 tile
            int row = eoff >> 6, col = eoff & 63;
            g2l16(Amat + (m0 + row) * (size_t)K + (k0 + col), &sA[chunk * 512]);
            g2l16(BT   + (size_t)(n0 + row) * K + (k0 + col), &sB[chunk * 512]);
        }
        __syncthreads();
        #pragma unroll
        for (int q2 = 0; q2 < 2; ++q2) {
            const int kk = q2 * 32 + q * 8;
            f16x8 af[4], bf[4];
            #pragma unroll
            for (int mi = 0; mi < 4; ++mi)
                af[mi] = *(const f16x8*)&sA[(wm * 64 + mi * 16 + r16) * 64 + kk];
            #pragma unroll
            for (int ni = 0; ni < 4; ++ni)
                bf[ni] = *(const f16x8*)&sB[(wn * 64 + ni * 16 + r16) * 64 + kk];
            #pragma unroll
            for (int mi = 0; mi < 4; ++mi)
                #pragma unroll
                for (int ni = 0; ni < 4; ++ni)
                    acc[mi][ni] = __builtin_amdgcn_mfma_f32_16x16x32_f16(
                        af[mi], bf[ni], acc[mi][ni], 0, 0, 0);
        }
        __syncthreads();
    }

    // epilogue: lane owns col b = n0+wn*64+ni*16+r16, rows m = mbase..mbase+3
    #pragma unroll
    for (int mi = 0; mi < 4; ++mi) {
        #pragma unroll
        for (int ni = 0; ni < 4; ++ni) {
            const int bcol = n0 + wn * 64 + ni * 16 + r16;
            const size_t mbase = m0 + wm * 64 + mi * 16 + q * 4;
            if (MODE == 0) {
                float v[4];
                #pragma unroll
                for (int p = 0; p < 4; ++p) {
                    float t = acc[mi][ni][p];
                    if (bcol < B) t += noise[(mbase + p) * B + bcol];
                    v[p] = t;
                }
                H4 h { (_Float16)v[0], (_Float16)v[1], (_Float16)v[2], (_Float16)v[3] };
                *(H4*)&tT[(size_t)bcol * NM + mbase] = h;
            } else {
                const float g = gamma[iter];
                #pragma unroll
                for (int p = 0; p < 4; ++p) {
                    float sv = (bcol < s_ld) ? sprev[(mbase + p) * (size_t)s_ld + bcol] : 0.0f;
                    r[(mbase + p) * (size_t)BP + bcol] = fmaf(g, acc[mi][ni][p], sv);
                }
            }
        }
    }
}

// per-column ||t||^2 -> tau2 -> coef = SCALE/tau2
__global__ __launch_bounds__(256) void tau2_kern(
        const _Float16* __restrict__ tT, const float* __restrict__ sc,
        const float* __restrict__ gamma, int iter, float* __restrict__ coef) {
    const int b = blockIdx.x;
    const _Float16* row = &tT[(size_t)b * NM];
    float sum = 0.0f;
    for (int i = threadIdx.x * 8; i < NM; i += 256 * 8) {
        f16x8 v = *(const f16x8*)&row[i];
        #pragma unroll
        for (int k = 0; k < 8; ++k) { float f = (float)v[k]; sum = fmaf(f, f, sum); }
    }
    __shared__ float red[4];
    #pragma unroll
    for (int o = 32; o > 0; o >>= 1) sum += __shfl_down(sum, o);
    if ((threadIdx.x & 63) == 0) red[threadIdx.x >> 6] = sum;
    __syncthreads();
    if (threadIdx.x == 0) {
        float tot = red[0] + red[1] + red[2] + red[3];
        float taa = sc[0], tww = sc[1];
        float g = gamma[iter];
        float v2 = (tot - (float)MSEC * SIGMA2) / taa;
        float tau2 = v2 / (float)NN * ((float)NN + (g * g - 2.0f * g) * (float)MSEC)
                   + g * g * tww * SIGMA2 / (float)NN;
        coef[b] = SCALE / tau2;
    }
}

// per-section softmax; write s (fp32), optional d_out, optional next u^T (f16)
__global__ __launch_bounds__(128) void shrink_kern(
        const float* __restrict__ r, const float* __restrict__ coef,
        const float* __restrict__ x, float* __restrict__ s_cur,
        float* __restrict__ out, _Float16* __restrict__ uT,
        int write_u, int write_out) {
    const int j  = blockIdx.x;
    const int b  = blockIdx.y * 128 + threadIdx.x;
    const int m0 = j * MSEC;
    const float c = coef[b];
    float v[MSEC];
    float mx = -1e30f;
    #pragma unroll
    for (int i = 0; i < MSEC; ++i) {
        v[i] = r[(size_t)(m0 + i) * BP + b] * c;
        mx = fmaxf(mx, v[i]);
    }
    float sum = 0.0f;
    #pragma unroll
    for (int i = 0; i < MSEC; ++i) {
        v[i] = exp2f((v[i] - mx) * 1.44269504f);
        sum += v[i];
    }
    const float inv = 1.0f / sum;
    _Float16 uv[MSEC];
    #pragma unroll
    for (int i = 0; i < MSEC; ++i) {
        float sv = v[i] * inv;
        s_cur[(size_t)(m0 + i) * BP + b] = sv;
        if (write_out && b < B) out[(size_t)(m0 + i) * B + b] = sv;
        uv[i] = (b < B) ? (_Float16)(x[(size_t)(m0 + i) * B + b] - sv) : (_Float16)0.0f;
    }
    if (write_u) {
        f16x8* dst = (f16x8*)&uT[(size_t)b * NN + m0];
        const f16x8* src8 = (const f16x8*)uv;
        #pragma unroll
        for (int cI = 0; cI < 4; ++cI) dst[cI] = src8[cI];
    }
}

// ---------------- launch ----------------
extern "C" void kernel_launch(void* const* d_in, const int* in_sizes, int n_in,
                              void* d_out, int out_size, void* d_ws, size_t ws_size,
                              hipStream_t stream) {
    const float* x     = (const float*)d_in[0];
    const float* s_in  = (const float*)d_in[1];
    const float* noise = (const float*)d_in[2];
    const float* A     = (const float*)d_in[3];
    const float* W     = (const float*)d_in[4];
    const float* gamma = (const float*)d_in[5];
    // d_in[6] = max_itr (always 4) — loop count must be host-side constant.
    float* out = (float*)d_out;

    char* ws = (char*)d_ws;
    _Float16* A16  = (_Float16*)(ws + OFF_A16);
    _Float16* W16  = (_Float16*)(ws + OFF_W16);
    _Float16* uT   = (_Float16*)(ws + OFF_UT);
    _Float16* tT   = (_Float16*)(ws + OFF_TT);
    float*    rbuf = (float*)(ws + OFF_R);
    float*    sbuf = (float*)(ws + OFF_S);
    float*    sc   = (float*)(ws + OFF_SC);   // [0]=taa [1]=tww
    float*    coef = sc + 16;                 // [512]

    init_scalars<<<1, 64, 0, stream>>>(sc);
    convert_f16_sq<<<2048, 256, 0, stream>>>(A, A16, (size_t)NM * NN / 4, &sc[0]);
    convert_f16_sq<<<2048, 256, 0, stream>>>(W, W16, (size_t)NN * NM / 4, &sc[1]);
    make_u0T<<<dim3(LSEC, BP / 128), 128, 0, stream>>>(x, s_in, uT);

    for (int it = 0; it < ITERS; ++it) {
        gemm_kern<0><<<dim3(NM / 128, BP / 128), 256, 0, stream>>>(
            A16, uT, NN, noise, tT, nullptr, 0, nullptr, 0, nullptr);
        tau2_kern<<<BP, 256, 0, stream>>>(tT, sc, gamma, it, coef);
        gemm_kern<1><<<dim3(NN / 128, BP / 128), 256, 0, stream>>>(
            W16, tT, NM, nullptr, nullptr,
            (it == 0) ? s_in : sbuf, (it == 0) ? B : BP,
            gamma, it, rbuf);
        shrink_kern<<<dim3(LSEC, BP / 128), 128, 0, stream>>>(
            rbuf, coef, x, sbuf, out, uT,
            (it < ITERS - 1) ? 1 : 0, (it == ITERS - 1) ? 1 : 0);
    }
}

// Round 2
// 2439.946 us; speedup vs baseline: 1.3869x; 1.3869x over previous
//
#include <hip/hip_runtime.h>
#include <stdint.h>
#include <math.h>

// ---------------- constants ----------------
constexpr int NN   = 16384;   // N = L*M
constexpr int NM   = 5120;    // n (measurements)
constexpr int B    = 500;     // batch
constexpr int BP   = 512;     // padded batch
constexpr int LSEC = 512;     // sections
constexpr int MSEC = 32;      // section size
constexpr float SIGMA2 = 0.2f;
constexpr float SCALE  = 3.1622776601683795f; // sqrt(n*P/L) = sqrt(10)
constexpr int ITERS   = 4;
constexpr int SPLIT_T = 4;    // split-K for t-GEMM (K=16384 -> 4096/seg)
constexpr int SPLIT_R = 2;    // split-K for r-GEMM (K=5120  -> 2560/seg)

// ---------------- workspace layout (bytes), total ~458 MB ----------------
constexpr size_t OFF_A16 = 0;                                  // f16 A [5120][16384]
constexpr size_t SZ_A16  = (size_t)NM * NN * 2;
constexpr size_t OFF_W16 = OFF_A16 + SZ_A16;                   // f16 W [16384][5120]
constexpr size_t SZ_W16  = (size_t)NN * NM * 2;
constexpr size_t OFF_UT  = OFF_W16 + SZ_W16;                   // f16 u^T [512][16384]
constexpr size_t SZ_UT   = (size_t)BP * NN * 2;
constexpr size_t OFF_TT  = OFF_UT + SZ_UT;                     // f16 t^T [512][5120]
constexpr size_t SZ_TT   = (size_t)BP * NM * 2;
// Union region: Pt [4][512][5120] f32 (41.9 MB) OR Pr [2][16384][512] f32 (67.1 MB)
// Lifetimes disjoint within an iteration: Pt (gemm0->combine), Pr (gemm1->shrink).
constexpr size_t OFF_P   = OFF_TT + SZ_TT;
constexpr size_t SZ_P    = (size_t)SPLIT_R * NN * BP * 4;
constexpr size_t OFF_S   = OFF_P + SZ_P;                       // f32 s [16384][512]
constexpr size_t SZ_S    = (size_t)NN * BP * 4;
constexpr size_t OFF_SC  = OFF_S + SZ_S;                       // scalars + coef + sq

typedef _Float16 f16x8 __attribute__((ext_vector_type(8)));
typedef float    f32x4 __attribute__((ext_vector_type(4)));

// global -> LDS direct copy, 16 B per lane; LDS dst wave-uniform, HW writes
// lane's 16 B at (base + lane*16).
typedef const uint32_t __attribute__((address_space(1)))* gp_t;
typedef uint32_t       __attribute__((address_space(3)))* lp_t;
__device__ __forceinline__ void g2l16(const void* g, void* l) {
    __builtin_amdgcn_global_load_lds((gp_t)(uintptr_t)g,
                                     (lp_t)(uint32_t)(uintptr_t)l, 16, 0, 0);
}

// ---------------- small kernels ----------------
__global__ void init_scalars(float* sc) {
    if (threadIdx.x < 2) sc[threadIdx.x] = 0.0f;
}

__global__ void iter_init(float* sq) {
    if (threadIdx.x < BP) sq[threadIdx.x] = 0.0f;
}

// fp32 -> fp16 convert, fused sum-of-squares reduction (taa / tww)
__global__ __launch_bounds__(256) void convert_f16_sq(
        const float* __restrict__ src, _Float16* __restrict__ dst,
        size_t n4, float* __restrict__ accum) {
    size_t i = (size_t)blockIdx.x * blockDim.x + threadIdx.x;
    size_t stride = (size_t)gridDim.x * blockDim.x;
    float sum = 0.0f;
    for (size_t j = i; j < n4; j += stride) {
        const float4 v = ((const float4*)src)[j];
        sum = fmaf(v.x, v.x, fmaf(v.y, v.y, fmaf(v.z, v.z, fmaf(v.w, v.w, sum))));
        _Float16 h[4] = {(_Float16)v.x, (_Float16)v.y, (_Float16)v.z, (_Float16)v.w};
        ((float2*)dst)[j] = *(float2*)h;
    }
    #pragma unroll
    for (int o = 32; o > 0; o >>= 1) sum += __shfl_down(sum, o);
    if ((threadIdx.x & 63) == 0) atomicAdd(accum, sum);
}

// u0^T[b][k] = f16(x[k][b] - s_in[k][b]), zero-padded for b >= 500
__global__ __launch_bounds__(128) void make_u0T(
        const float* __restrict__ x, const float* __restrict__ s,
        _Float16* __restrict__ uT) {
    int j  = blockIdx.x;
    int b  = blockIdx.y * 128 + threadIdx.x;
    int m0 = j * MSEC;
    _Float16 vals[MSEC];
    if (b < B) {
        #pragma unroll
        for (int i = 0; i < MSEC; ++i) {
            size_t idx = (size_t)(m0 + i) * B + b;
            vals[i] = (_Float16)(x[idx] - s[idx]);
        }
    } else {
        #pragma unroll
        for (int i = 0; i < MSEC; ++i) vals[i] = (_Float16)0.0f;
    }
    f16x8* dst = (f16x8*)&uT[(size_t)b * NN + m0];
    const f16x8* v8 = (const f16x8*)vals;
    #pragma unroll
    for (int c = 0; c < 4; ++c) dst[c] = v8[c];
}

// ---------------- split-K GEMM ----------------
// MODE 0: Pt[seg][b][m] += A16[m][:] . u^T[b][:]   (+noise in seg 0)
// MODE 1: Pr[seg][m][b]  = W16[m][:] . t^T[b][:]
// LDS tiles XOR-swizzled: tile column-group g (16 B) of row r stored at slot
// g^(r&7); reads spread 16 lanes over all 32 banks (2-way aliasing = free).
template <int MODE>
__global__ __launch_bounds__(256) void gemm_kern(
        const _Float16* __restrict__ Amat, const _Float16* __restrict__ BT,
        int K, int Kseg, const float* __restrict__ noise,
        float* __restrict__ Pout) {
    __shared__ _Float16 sA[128 * 64];   // [row][kslot], swizzled
    __shared__ _Float16 sB[128 * 64];
    const int tid  = threadIdx.x;
    const int lane = tid & 63;
    const int wave = tid >> 6;
    const int wm = wave >> 1, wn = wave & 1;     // 2x2 wave grid, 64x64 each
    const size_t m0 = (size_t)blockIdx.x * 128;
    const int    n0 = blockIdx.y * 128;
    const int    seg = blockIdx.z;
    const int r16 = lane & 15, q = lane >> 4;
    const int sx = r16 & 7;

    f32x4 acc[4][4] = {};

    const int kbeg = seg * Kseg;
    for (int k0 = kbeg; k0 < kbeg + Kseg; k0 += 64) {
        #pragma unroll
        for (int j = 0; j < 4; ++j) {
            int chunk = wave * 4 + j;             // 0..15, wave-uniform
            int off   = chunk * 512 + lane * 8;   // halves within 128x64 tile
            int row   = off >> 6;
            int col   = ((((off >> 3) & 7) ^ (row & 7)) << 3);  // XOR swizzle
            g2l16(Amat + (m0 + row) * (size_t)K + (k0 + col), &sA[chunk * 512]);
            g2l16(BT   + (size_t)(n0 + row) * K + (k0 + col), &sB[chunk * 512]);
        }
        __syncthreads();
        #pragma unroll
        for (int q2 = 0; q2 < 2; ++q2) {
            const int cg = q2 * 4 + q;                 // column-group 0..7
            const int colsw = ((cg ^ sx) << 3);        // swizzled read column
            f16x8 af[4], bf[4];
            #pragma unroll
            for (int mi = 0; mi < 4; ++mi)
                af[mi] = *(const f16x8*)&sA[(wm * 64 + mi * 16 + r16) * 64 + colsw];
            #pragma unroll
            for (int ni = 0; ni < 4; ++ni)
                bf[ni] = *(const f16x8*)&sB[(wn * 64 + ni * 16 + r16) * 64 + colsw];
            #pragma unroll
            for (int mi = 0; mi < 4; ++mi)
                #pragma unroll
                for (int ni = 0; ni < 4; ++ni)
                    acc[mi][ni] = __builtin_amdgcn_mfma_f32_16x16x32_f16(
                        af[mi], bf[ni], acc[mi][ni], 0, 0, 0);
        }
        __syncthreads();
    }

    // epilogue: lane owns col b = n0+wn*64+ni*16+r16, rows m = mbase..mbase+3
    #pragma unroll
    for (int mi = 0; mi < 4; ++mi) {
        #pragma unroll
        for (int ni = 0; ni < 4; ++ni) {
            const int bcol = n0 + wn * 64 + ni * 16 + r16;
            const size_t mbase = m0 + wm * 64 + mi * 16 + q * 4;
            if (MODE == 0) {
                f32x4 v;
                #pragma unroll
                for (int p = 0; p < 4; ++p) {
                    float t = acc[mi][ni][p];
                    if (seg == 0 && bcol < B) t += noise[(mbase + p) * B + bcol];
                    v[p] = t;
                }
                *(f32x4*)&Pout[((size_t)seg * BP + bcol) * NM + mbase] = v;
            } else {
                #pragma unroll
                for (int p = 0; p < 4; ++p)
                    Pout[((size_t)seg * NN + mbase + p) * BP + bcol] = acc[mi][ni][p];
            }
        }
    }
}

// sum 4 t-partials -> fp16 t^T; fused per-column ||t||^2 (one atomic per wave)
__global__ __launch_bounds__(256) void combine_t(
        const float* __restrict__ Pt, _Float16* __restrict__ tT,
        float* __restrict__ sq) {
    const int g  = blockIdx.x * 256 + threadIdx.x;
    const int b  = g / 640;              // 640 threads per batch column (10 waves)
    const int mi = (g - b * 640) * 8;
    float v[8] = {};
    #pragma unroll
    for (int s = 0; s < SPLIT_T; ++s) {
        const f32x4* p = (const f32x4*)&Pt[((size_t)s * BP + b) * NM + mi];
        f32x4 a = p[0], c = p[1];
        #pragma unroll
        for (int i = 0; i < 4; ++i) { v[i] += a[i]; v[4 + i] += c[i]; }
    }
    f16x8 h;
    float ss = 0.0f;
    #pragma unroll
    for (int i = 0; i < 8; ++i) { h[i] = (_Float16)v[i]; ss = fmaf(v[i], v[i], ss); }
    *(f16x8*)&tT[(size_t)b * NM + mi] = h;
    #pragma unroll
    for (int o = 32; o > 0; o >>= 1) ss += __shfl_down(ss, o);
    if ((threadIdx.x & 63) == 0) atomicAdd(&sq[b], ss);  // wave is b-uniform (640%64==0)
}

__global__ void tau2_fin(const float* __restrict__ sq, const float* __restrict__ sc,
                         const float* __restrict__ gamma, int it,
                         float* __restrict__ coef) {
    int b = threadIdx.x;
    if (b >= BP) return;
    float tot = sq[b];
    float taa = sc[0], tww = sc[1];
    float g = gamma[it];
    float v2 = (tot - (float)MSEC * SIGMA2) / taa;
    float tau2 = v2 / (float)NN * ((float)NN + (g * g - 2.0f * g) * (float)MSEC)
               + g * g * tww * SIGMA2 / (float)NN;
    coef[b] = SCALE / tau2;
}

// r = sprev + g*(Pr0+Pr1); per-section softmax; write s, optional out / next u^T
__global__ __launch_bounds__(128) void shrink_kern(
        const float* __restrict__ Pr, const float* __restrict__ coef,
        const float* __restrict__ gamma, int it,
        const float* __restrict__ sprev, int s_ld,
        const float* __restrict__ x, float* __restrict__ s_cur,
        float* __restrict__ out, _Float16* __restrict__ uT,
        int write_u, int write_out) {
    const int j  = blockIdx.x;
    const int b  = blockIdx.y * 128 + threadIdx.x;
    const int m0 = j * MSEC;
    const float c = coef[b];
    const float g = gamma[it];
    float v[MSEC];
    float mx = -1e30f;
    #pragma unroll
    for (int i = 0; i < MSEC; ++i) {
        const size_t m = m0 + i;
        float p  = Pr[m * BP + b] + Pr[(size_t)NN * BP + m * BP + b];
        float sv = (b < s_ld) ? sprev[m * (size_t)s_ld + b] : 0.0f;
        v[i] = fmaf(g, p, sv) * c;
        mx = fmaxf(mx, v[i]);
    }
    float sum = 0.0f;
    #pragma unroll
    for (int i = 0; i < MSEC; ++i) {
        v[i] = exp2f((v[i] - mx) * 1.44269504f);
        sum += v[i];
    }
    const float inv = 1.0f / sum;
    _Float16 uv[MSEC];
    #pragma unroll
    for (int i = 0; i < MSEC; ++i) {
        float sv = v[i] * inv;
        s_cur[(size_t)(m0 + i) * BP + b] = sv;
        if (write_out && b < B) out[(size_t)(m0 + i) * B + b] = sv;
        uv[i] = (b < B) ? (_Float16)(x[(size_t)(m0 + i) * B + b] - sv) : (_Float16)0.0f;
    }
    if (write_u) {
        f16x8* dst = (f16x8*)&uT[(size_t)b * NN + m0];
        const f16x8* src8 = (const f16x8*)uv;
        #pragma unroll
        for (int cI = 0; cI < 4; ++cI) dst[cI] = src8[cI];
    }
}

// ---------------- launch ----------------
extern "C" void kernel_launch(void* const* d_in, const int* in_sizes, int n_in,
                              void* d_out, int out_size, void* d_ws, size_t ws_size,
                              hipStream_t stream) {
    const float* x     = (const float*)d_in[0];
    const float* s_in  = (const float*)d_in[1];
    const float* noise = (const float*)d_in[2];
    const float* A     = (const float*)d_in[3];
    const float* W     = (const float*)d_in[4];
    const float* gamma = (const float*)d_in[5];
    float* out = (float*)d_out;

    char* ws = (char*)d_ws;
    _Float16* A16  = (_Float16*)(ws + OFF_A16);
    _Float16* W16  = (_Float16*)(ws + OFF_W16);
    _Float16* uT   = (_Float16*)(ws + OFF_UT);
    _Float16* tT   = (_Float16*)(ws + OFF_TT);
    float*    Pbuf = (float*)(ws + OFF_P);    // Pt / Pr union
    float*    sbuf = (float*)(ws + OFF_S);
    float*    sc   = (float*)(ws + OFF_SC);   // [0]=taa [1]=tww
    float*    coef = sc + 16;                 // [512]
    float*    sq   = coef + BP;               // [512]

    init_scalars<<<1, 64, 0, stream>>>(sc);
    convert_f16_sq<<<2048, 256, 0, stream>>>(A, A16, (size_t)NM * NN / 4, &sc[0]);
    convert_f16_sq<<<2048, 256, 0, stream>>>(W, W16, (size_t)NN * NM / 4, &sc[1]);
    make_u0T<<<dim3(LSEC, BP / 128), 128, 0, stream>>>(x, s_in, uT);

    for (int it = 0; it < ITERS; ++it) {
        iter_init<<<1, BP, 0, stream>>>(sq);
        gemm_kern<0><<<dim3(NM / 128, BP / 128, SPLIT_T), 256, 0, stream>>>(
            A16, uT, NN, NN / SPLIT_T, noise, Pbuf);
        combine_t<<<(BP * (NM / 8)) / 256, 256, 0, stream>>>(Pbuf, tT, sq);
        tau2_fin<<<1, BP, 0, stream>>>(sq, sc, gamma, it, coef);
        gemm_kern<1><<<dim3(NN / 128, BP / 128, SPLIT_R), 256, 0, stream>>>(
            W16, tT, NM, NM / SPLIT_R, nullptr, Pbuf);
        shrink_kern<<<dim3(LSEC, BP / 128), 128, 0, stream>>>(
            Pbuf, coef, gamma, it,
            (it == 0) ? s_in : sbuf, (it == 0) ? B : BP,
            x, sbuf, out, uT,
            (it < ITERS - 1) ? 1 : 0, (it == ITERS - 1) ? 1 : 0);
    }
}